// Round 7
// baseline (832.969 us; speedup 1.0000x reference)
//
#include <hip/hip_runtime.h>

#define SEMEME_SIZE 2048
#define D_MODEL 512
#define MAX_NNZ 64
#define ROW_MASK (SEMEME_SIZE - 1)

typedef float vf4 __attribute__((ext_vector_type(4)));
typedef unsigned short vu8 __attribute__((ext_vector_type(8)));

// ======================= DIAGNOSTIC + FIX ROUND ============================
// Two-pass, both rep-amplified so each pass gets its own rocprof row:
//   pass1 x8  : ballot-compact gather (pure 105 MB HBM stream) -> CSR in ws
//   pass2 x16 : W[:,16-dim slice] staged as bf16 in 64 KB LDS (immune to the
//               L2 thrash that made W reads fall to fabric/L3 = R6's 3 TB/s,
//               39%-peak plateau), 32 tokens per wave-instr accumulate.
// ===========================================================================

// ---------------- Pass 1: extract (wave per token) ----------------
#define P1_WPB 4
#define P1_BLOCK (P1_WPB * 64)

__global__ __launch_bounds__(P1_BLOCK) void pass1_extract(
    const int* __restrict__ x,
    const float* __restrict__ w2s,
    int* __restrict__ counts,
    unsigned short* __restrict__ idxbuf,
    int n_tokens, int reps)
{
    const int wave = blockIdx.x * P1_WPB + (threadIdx.x >> 6);
    const int lane = threadIdx.x & 63;
    if (wave >= n_tokens) return;

    const int wid = x[wave];
    const vf4* __restrict__ row4 = (const vf4*)(w2s + (size_t)wid * SEMEME_SIZE);
    unsigned short* __restrict__ myidx = idxbuf + (size_t)wave * MAX_NNZ;
    const unsigned long long lt = (1ull << lane) - 1ull;

    #pragma unroll 1
    for (int r = 0; r < reps; ++r) {
        __asm__ volatile("" ::: "memory");  // defeat cross-rep CSE
        int base = 0;
        #pragma unroll
        for (int c = 0; c < 8; ++c) {
            const vf4 v = __builtin_nontemporal_load(&row4[c * 64 + lane]);
            const float vv[4] = { v.x, v.y, v.z, v.w };
            #pragma unroll
            for (int j = 0; j < 4; ++j) {
                const bool nz = (vv[j] != 0.0f);
                const unsigned long long m = __ballot(nz);
                if (nz) {
                    const int pos = base + __popcll(m & lt);
                    if (pos < MAX_NNZ)
                        myidx[pos] = (unsigned short)(c * 256 + lane * 4 + j);
                }
                base += __popcll(m);
            }
        }
        if (lane == 0) counts[wave] = base;
    }
}

// ---------------- Pass 2: embed from LDS-staged bf16 W slice ----------------
#define DSLICE 16
#define NSLICE (D_MODEL / DSLICE)   // 32
#define P2_TOK 2048                 // tokens per block
#define P2_BLOCK 512                // 8 waves

__device__ __forceinline__ unsigned short f2bf(float f) {
    unsigned u = __float_as_uint(f);
    u += 0x7fffu + ((u >> 16) & 1u);   // RNE
    return (unsigned short)(u >> 16);
}

__global__ __launch_bounds__(P2_BLOCK) void pass2_embed(
    const int* __restrict__ counts,
    const unsigned short* __restrict__ idxbuf,
    const float* __restrict__ W,
    float* __restrict__ out,
    int n_tokens, int reps)
{
    __shared__ unsigned short sWh[SEMEME_SIZE * DSLICE];  // 64 KB bf16 slice

    const int slice = blockIdx.x & (NSLICE - 1);
    const int group = blockIdx.x / NSLICE;
    const int d0    = slice * DSLICE;
    const int tid   = threadIdx.x;
    const int waveid = tid >> 6;
    const int lane   = tid & 63;
    const int tok32  = lane >> 1;   // 0..31: token sub-slot within wave
    const int j2     = lane & 1;    // which 8-dim half of the slice

    #pragma unroll 1
    for (int r = 0; r < reps; ++r) {
        __syncthreads();  // prior rep's readers done before restaging
        // ---- stage W[:, d0:d0+16] -> bf16 LDS (RNE) ----------------------
        for (int f4 = tid; f4 < SEMEME_SIZE * (DSLICE / 4); f4 += P2_BLOCK) {
            const int k = f4 >> 2, j4 = f4 & 3;
            const vf4 w = *((const vf4*)(W + (size_t)k * D_MODEL + d0) + j4);
            unsigned short* p = &sWh[k * DSLICE + j4 * 4];
            p[0] = f2bf(w.x); p[1] = f2bf(w.y); p[2] = f2bf(w.z); p[3] = f2bf(w.w);
        }
        __syncthreads();

        // ---- token loop: 32 tokens per wave-instr ------------------------
        const int tkbase = group * P2_TOK + waveid * (P2_TOK / 8);
        #pragma unroll 1
        for (int it = 0; it < (P2_TOK / 8) / 32; ++it) {   // 8 iterations
            const int tk = tkbase + it * 32 + tok32;
            if (tk >= n_tokens) continue;
            const int cnt = counts[tk];
            const int n = cnt < MAX_NNZ ? cnt : MAX_NNZ;
            const unsigned short* __restrict__ myi = idxbuf + (size_t)tk * MAX_NNZ;

            vf4 a0 = {0.f, 0.f, 0.f, 0.f};
            vf4 a1 = {0.f, 0.f, 0.f, 0.f};

            for (int i = 0; i < n; i += 4) {
                const unsigned long long q = *(const unsigned long long*)(myi + i);
                #pragma unroll
                for (int j = 0; j < 4; ++j) {
                    if (i + j < n) {
                        // mask guards 0xAA ws-poison in slots >= cnt (never
                        // hit: i+j < n) and keeps any stray read in-bounds
                        const int k = (int)((q >> (16 * j)) & 0xffffull) & ROW_MASK;
                        const vu8 h = *(const vu8*)&sWh[k * DSLICE + j2 * 8];
                        a0.x += __uint_as_float((unsigned)h[0] << 16);
                        a0.y += __uint_as_float((unsigned)h[1] << 16);
                        a0.z += __uint_as_float((unsigned)h[2] << 16);
                        a0.w += __uint_as_float((unsigned)h[3] << 16);
                        a1.x += __uint_as_float((unsigned)h[4] << 16);
                        a1.y += __uint_as_float((unsigned)h[5] << 16);
                        a1.z += __uint_as_float((unsigned)h[6] << 16);
                        a1.w += __uint_as_float((unsigned)h[7] << 16);
                    }
                }
            }

            const float scale = 22.62741699796952f / ((float)cnt + 1e-6f);
            a0 *= scale; a1 *= scale;
            vf4* __restrict__ o = (vf4*)(out + (size_t)tk * D_MODEL + d0 + j2 * 8);
            __builtin_nontemporal_store(a0, &o[0]);
            __builtin_nontemporal_store(a1, &o[1]);
        }
    }
}

extern "C" void kernel_launch(void* const* d_in, const int* in_sizes, int n_in,
                              void* d_out, int out_size, void* d_ws, size_t ws_size,
                              hipStream_t stream) {
    const int*   x   = (const int*)d_in[0];     // [B*S] token ids
    const float* w2s = (const float*)d_in[1];   // [VOCAB, SEMEME_SIZE], values {0,1}
    const float* W   = (const float*)d_in[2];   // [SEMEME_SIZE, D_MODEL]
    float* out = (float*)d_out;                 // [B*S, D_MODEL]

    const int n_tokens = in_sizes[0];           // 16384

    // ws layout: counts int[n_tokens] | idxbuf u16[n_tokens][MAX_NNZ]
    int* counts = (int*)d_ws;
    unsigned short* idxbuf = (unsigned short*)((char*)d_ws + (size_t)n_tokens * sizeof(int));

    const int p1_blocks = (n_tokens + P1_WPB - 1) / P1_WPB;
    const int groups    = (n_tokens + P2_TOK - 1) / P2_TOK;

    pass1_extract<<<p1_blocks, P1_BLOCK, 0, stream>>>(x, w2s, counts, idxbuf,
                                                      n_tokens, /*reps=*/8);
    pass2_embed<<<groups * NSLICE, P2_BLOCK, 0, stream>>>(counts, idxbuf, W, out,
                                                          n_tokens, /*reps=*/16);
}

// Round 8
// 340.312 us; speedup vs baseline: 2.4477x; 2.4477x over previous
//
#include <hip/hip_runtime.h>

#define SEMEME_SIZE 2048
#define D_MODEL 512
#define MAX_NNZ 64
#define ROW_MASK (SEMEME_SIZE - 1)

typedef float vf4 __attribute__((ext_vector_type(4)));
typedef unsigned short vu8 __attribute__((ext_vector_type(8)));

__device__ __forceinline__ unsigned long long f2bf_u(float f) {
    unsigned u = __float_as_uint(f);
    u += 0x7fffu + ((u >> 16) & 1u);   // RNE
    return (unsigned long long)(u >> 16);
}

// ---------------------------------------------------------------------------
// pass0: W f32 -> bf16 (RNE) into ws. 4 MB read + 2 MB write, ~1 us.
// Halves pass2's L2 read traffic and makes one W row == one dwordx4/lane.
// ---------------------------------------------------------------------------
__global__ __launch_bounds__(256) void pass0_convert(
    const float* __restrict__ W, unsigned short* __restrict__ Wh)
{
    const int i = blockIdx.x * 256 + threadIdx.x;        // vf4 index (262144 total)
    const vf4 w = __builtin_nontemporal_load((const vf4*)W + i);
    const unsigned long long p = f2bf_u(w.x) | (f2bf_u(w.y) << 16)
                               | (f2bf_u(w.z) << 32) | (f2bf_u(w.w) << 48);
    ((unsigned long long*)Wh)[i] = p;
}

// ---------------------------------------------------------------------------
// pass1: wave per token. Ballot-compact the 0/1 row of word2sememe[x[t]]
// into counts[t] (exact popcount) + up to MAX_NNZ u16 indices. Pure
// 105-134 MB HBM stream, measured at its ~17.6 us floor in R7.
// ---------------------------------------------------------------------------
#define P1_WPB 4
#define P1_BLOCK (P1_WPB * 64)

__global__ __launch_bounds__(P1_BLOCK) void pass1_extract(
    const int* __restrict__ x,
    const float* __restrict__ w2s,
    int* __restrict__ counts,
    unsigned short* __restrict__ idxbuf,
    int n_tokens)
{
    const int wave = blockIdx.x * P1_WPB + (threadIdx.x >> 6);
    const int lane = threadIdx.x & 63;
    if (wave >= n_tokens) return;

    const int wid = x[wave];
    const vf4* __restrict__ row4 = (const vf4*)(w2s + (size_t)wid * SEMEME_SIZE);
    unsigned short* __restrict__ myidx = idxbuf + (size_t)wave * MAX_NNZ;
    const unsigned long long lt = (1ull << lane) - 1ull;

    int base = 0;
    #pragma unroll
    for (int c = 0; c < 8; ++c) {
        const vf4 v = __builtin_nontemporal_load(&row4[c * 64 + lane]);
        const float vv[4] = { v.x, v.y, v.z, v.w };
        #pragma unroll
        for (int j = 0; j < 4; ++j) {
            const bool nz = (vv[j] != 0.0f);
            const unsigned long long m = __ballot(nz);
            if (nz) {
                const int pos = base + __popcll(m & lt);
                if (pos < MAX_NNZ)
                    myidx[pos] = (unsigned short)(c * 256 + lane * 4 + j);
            }
            base += __popcll(m);
        }
    }
    if (lane == 0) counts[wave] = base;
}

// ---------------------------------------------------------------------------
// pass2: wave per token. Each nonzero index is readlane-broadcast to an SGPR;
// all 64 lanes then load the SAME bf16 W row -> one fully-coalesced 1 KB
// wave access (dwordx4/lane), L2-hit, zero bank conflicts, zero LDS.
// Floor: max(33.5 MB out writes ~5.3 us, 171 MB L2 W reads ~5 us).
// ---------------------------------------------------------------------------
#define P2_WPB 4
#define P2_BLOCK (P2_WPB * 64)

__global__ __launch_bounds__(P2_BLOCK) void pass2_embed(
    const int* __restrict__ counts,
    const unsigned short* __restrict__ idxbuf,
    const unsigned short* __restrict__ Wh,
    float* __restrict__ out,
    int n_tokens)
{
    const int wave = blockIdx.x * P2_WPB + (threadIdx.x >> 6);
    const int lane = threadIdx.x & 63;
    if (wave >= n_tokens) return;

    const int cnt = counts[wave];
    const int n = cnt < MAX_NNZ ? cnt : MAX_NNZ;
    // lane i holds slot i; 0xAA ws-poison in slots >= cnt is never selected
    const int myk = (int)idxbuf[(size_t)wave * MAX_NNZ + lane] & ROW_MASK;

    const vu8* __restrict__ Wrow = (const vu8*)Wh + lane;  // row stride 64 vu8

    vf4 a0 = {0.f, 0.f, 0.f, 0.f};
    vf4 a1 = {0.f, 0.f, 0.f, 0.f};

    for (int i = 0; i < n; ++i) {
        const int k = __builtin_amdgcn_readlane(myk, i);   // wave-uniform SGPR
        const vu8 h = Wrow[(size_t)k * (D_MODEL / 8)];     // 1 KB wave load
        a0.x += __uint_as_float((unsigned)h[0] << 16);
        a0.y += __uint_as_float((unsigned)h[1] << 16);
        a0.z += __uint_as_float((unsigned)h[2] << 16);
        a0.w += __uint_as_float((unsigned)h[3] << 16);
        a1.x += __uint_as_float((unsigned)h[4] << 16);
        a1.y += __uint_as_float((unsigned)h[5] << 16);
        a1.z += __uint_as_float((unsigned)h[6] << 16);
        a1.w += __uint_as_float((unsigned)h[7] << 16);
    }

    const float scale = 22.62741699796952f / ((float)cnt + 1e-6f); // sqrt(512)/(sum+eps)
    a0 *= scale; a1 *= scale;

    vf4* __restrict__ o = (vf4*)(out + (size_t)wave * D_MODEL + lane * 8);
    __builtin_nontemporal_store(a0, &o[0]);
    __builtin_nontemporal_store(a1, &o[1]);
}

extern "C" void kernel_launch(void* const* d_in, const int* in_sizes, int n_in,
                              void* d_out, int out_size, void* d_ws, size_t ws_size,
                              hipStream_t stream) {
    const int*   x   = (const int*)d_in[0];     // [B*S] token ids
    const float* w2s = (const float*)d_in[1];   // [VOCAB, SEMEME_SIZE], values {0,1}
    const float* W   = (const float*)d_in[2];   // [SEMEME_SIZE, D_MODEL]
    float* out = (float*)d_out;                 // [B*S, D_MODEL]

    const int n_tokens = in_sizes[0];           // 16384

    // ws layout: counts int[n_tokens] | idxbuf u16[n_tokens*MAX_NNZ] | Wh bf16[2048*512]
    int* counts = (int*)d_ws;
    unsigned short* idxbuf = (unsigned short*)((char*)d_ws + (size_t)n_tokens * sizeof(int));
    unsigned short* Wh     = idxbuf + (size_t)n_tokens * MAX_NNZ;

    const int p1_blocks = (n_tokens + P1_WPB - 1) / P1_WPB;
    const int p2_blocks = (n_tokens + P2_WPB - 1) / P2_WPB;

    pass0_convert<<<(SEMEME_SIZE * D_MODEL / 4) / 256, 256, 0, stream>>>(W, Wh);
    pass1_extract<<<p1_blocks, P1_BLOCK, 0, stream>>>(x, w2s, counts, idxbuf, n_tokens);
    pass2_embed  <<<p2_blocks, P2_BLOCK, 0, stream>>>(counts, idxbuf, Wh, out, n_tokens);
}

// Round 9
// 335.194 us; speedup vs baseline: 2.4850x; 1.0153x over previous
//
#include <hip/hip_runtime.h>

#define SEMEME_SIZE 2048
#define D_MODEL 512
#define MAX_NNZ 64
#define ROW_MASK (SEMEME_SIZE - 1)

typedef float vf4 __attribute__((ext_vector_type(4)));
typedef unsigned short vu8 __attribute__((ext_vector_type(8)));

__device__ __forceinline__ unsigned long long f2bf_u(float f) {
    unsigned u = __float_as_uint(f);
    u += 0x7fffu + ((u >> 16) & 1u);   // RNE
    return (unsigned long long)(u >> 16);
}

__device__ __forceinline__ void bf8_acc(const vu8 h, vf4& a0, vf4& a1) {
    a0.x += __uint_as_float((unsigned)h[0] << 16);
    a0.y += __uint_as_float((unsigned)h[1] << 16);
    a0.z += __uint_as_float((unsigned)h[2] << 16);
    a0.w += __uint_as_float((unsigned)h[3] << 16);
    a1.x += __uint_as_float((unsigned)h[4] << 16);
    a1.y += __uint_as_float((unsigned)h[5] << 16);
    a1.z += __uint_as_float((unsigned)h[6] << 16);
    a1.w += __uint_as_float((unsigned)h[7] << 16);
}

// ---------------------------------------------------------------------------
// Kernel A = pass1 + fused pass0 (one dispatch instead of two):
//   blocks [0, p1_blocks)          : wave-per-token ballot-compact gather of
//                                    the 0/1 row -> counts + u16 indices.
//                                    Pure ~105-134 MB HBM stream (at floor,
//                                    measured 17.6 us/rep in R7).
//   blocks [p1_blocks, +1024)      : W f32 -> bf16 (RNE) into ws (6 MB,
//                                    overlaps the gather for free).
// ---------------------------------------------------------------------------
#define P1_WPB 4
#define P1_BLOCK (P1_WPB * 64)

__global__ __launch_bounds__(P1_BLOCK) void passA_extract_convert(
    const int* __restrict__ x,
    const float* __restrict__ w2s,
    const float* __restrict__ W,
    unsigned short* __restrict__ Wh,
    int* __restrict__ counts,
    unsigned short* __restrict__ idxbuf,
    int n_tokens, int p1_blocks)
{
    if ((int)blockIdx.x >= p1_blocks) {
        // ---- W conversion block (wave-uniform branch) --------------------
        const int i = ((int)blockIdx.x - p1_blocks) * P1_BLOCK + (int)threadIdx.x;
        const vf4 w = __builtin_nontemporal_load((const vf4*)W + i);
        const unsigned long long p = f2bf_u(w.x) | (f2bf_u(w.y) << 16)
                                   | (f2bf_u(w.z) << 32) | (f2bf_u(w.w) << 48);
        ((unsigned long long*)Wh)[i] = p;
        return;
    }

    const int wave = blockIdx.x * P1_WPB + (threadIdx.x >> 6);
    const int lane = threadIdx.x & 63;
    if (wave >= n_tokens) return;

    const int wid = x[wave];
    const vf4* __restrict__ row4 = (const vf4*)(w2s + (size_t)wid * SEMEME_SIZE);
    unsigned short* __restrict__ myidx = idxbuf + (size_t)wave * MAX_NNZ;
    const unsigned long long lt = (1ull << lane) - 1ull;

    int base = 0;
    #pragma unroll
    for (int c = 0; c < 8; ++c) {
        const vf4 v = __builtin_nontemporal_load(&row4[c * 64 + lane]);
        const float vv[4] = { v.x, v.y, v.z, v.w };
        #pragma unroll
        for (int j = 0; j < 4; ++j) {
            const bool nz = (vv[j] != 0.0f);
            const unsigned long long m = __ballot(nz);
            if (nz) {
                const int pos = base + __popcll(m & lt);
                if (pos < MAX_NNZ)
                    myidx[pos] = (unsigned short)(c * 256 + lane * 4 + j);
            }
            base += __popcll(m);
        }
    }
    if (lane == 0) counts[wave] = base;
}

// ---------------------------------------------------------------------------
// Kernel B (pass2): wave per token. readlane-broadcast each index; all 64
// lanes load the SAME 1 KB bf16 W row (one dwordx4/lane, coalesced, L2-hit).
// Row loop quad-pipelined: 4 readlanes + 4 loads issued before accumulating
// -> 4 independent loads in flight instead of one (R8's rolled loop exposed
// ~200 cyc L2 latency per iteration). Dual accumulator pairs shorten chains.
// ---------------------------------------------------------------------------
#define P2_WPB 4
#define P2_BLOCK (P2_WPB * 64)

__global__ __launch_bounds__(P2_BLOCK) void passB_embed(
    const int* __restrict__ counts,
    const unsigned short* __restrict__ idxbuf,
    const unsigned short* __restrict__ Wh,
    float* __restrict__ out,
    int n_tokens)
{
    const int wave = blockIdx.x * P2_WPB + (threadIdx.x >> 6);
    const int lane = threadIdx.x & 63;
    if (wave >= n_tokens) return;

    const int cnt = counts[wave];
    const int n = cnt < MAX_NNZ ? cnt : MAX_NNZ;
    // lane i holds slot i; 0xAA ws-poison in slots >= cnt never selected
    const int myk = (int)idxbuf[(size_t)wave * MAX_NNZ + lane] & ROW_MASK;

    const vu8* __restrict__ Wrow = (const vu8*)Wh + lane;  // row stride 64 vu8

    vf4 a0 = {0.f, 0.f, 0.f, 0.f}, a1 = {0.f, 0.f, 0.f, 0.f};
    vf4 b0 = {0.f, 0.f, 0.f, 0.f}, b1 = {0.f, 0.f, 0.f, 0.f};

    int i = 0;
    for (; i + 4 <= n; i += 4) {
        const int k0 = __builtin_amdgcn_readlane(myk, i + 0);
        const int k1 = __builtin_amdgcn_readlane(myk, i + 1);
        const int k2 = __builtin_amdgcn_readlane(myk, i + 2);
        const int k3 = __builtin_amdgcn_readlane(myk, i + 3);
        const vu8 h0 = Wrow[(size_t)k0 * (D_MODEL / 8)];   // 4 loads in flight
        const vu8 h1 = Wrow[(size_t)k1 * (D_MODEL / 8)];
        const vu8 h2 = Wrow[(size_t)k2 * (D_MODEL / 8)];
        const vu8 h3 = Wrow[(size_t)k3 * (D_MODEL / 8)];
        bf8_acc(h0, a0, a1);
        bf8_acc(h1, b0, b1);
        bf8_acc(h2, a0, a1);
        bf8_acc(h3, b0, b1);
    }
    for (; i < n; ++i) {
        const int k = __builtin_amdgcn_readlane(myk, i);
        bf8_acc(Wrow[(size_t)k * (D_MODEL / 8)], a0, a1);
    }
    a0 += b0; a1 += b1;

    const float scale = 22.62741699796952f / ((float)cnt + 1e-6f); // sqrt(512)/(sum+eps)
    a0 *= scale; a1 *= scale;

    vf4* __restrict__ o = (vf4*)(out + (size_t)wave * D_MODEL + lane * 8);
    __builtin_nontemporal_store(a0, &o[0]);
    __builtin_nontemporal_store(a1, &o[1]);
}

extern "C" void kernel_launch(void* const* d_in, const int* in_sizes, int n_in,
                              void* d_out, int out_size, void* d_ws, size_t ws_size,
                              hipStream_t stream) {
    const int*   x   = (const int*)d_in[0];     // [B*S] token ids
    const float* w2s = (const float*)d_in[1];   // [VOCAB, SEMEME_SIZE], values {0,1}
    const float* W   = (const float*)d_in[2];   // [SEMEME_SIZE, D_MODEL]
    float* out = (float*)d_out;                 // [B*S, D_MODEL]

    const int n_tokens = in_sizes[0];           // 16384

    // ws layout: counts int[n_tokens] | idxbuf u16[n_tokens*MAX_NNZ] | Wh bf16[2048*512]
    int* counts = (int*)d_ws;
    unsigned short* idxbuf = (unsigned short*)((char*)d_ws + (size_t)n_tokens * sizeof(int));
    unsigned short* Wh     = idxbuf + (size_t)n_tokens * MAX_NNZ;

    const int p1_blocks   = (n_tokens + P1_WPB - 1) / P1_WPB;              // 4096
    const int conv_blocks = (SEMEME_SIZE * D_MODEL / 4) / P1_BLOCK;        // 1024
    const int p2_blocks   = (n_tokens + P2_WPB - 1) / P2_WPB;              // 4096

    passA_extract_convert<<<p1_blocks + conv_blocks, P1_BLOCK, 0, stream>>>(
        x, w2s, W, Wh, counts, idxbuf, n_tokens, p1_blocks);
    passB_embed<<<p2_blocks, P2_BLOCK, 0, stream>>>(counts, idxbuf, Wh, out, n_tokens);
}